// Round 2
// baseline (776.000 us; speedup 1.0000x reference)
//
#include <hip/hip_runtime.h>
#include <hip/hip_bf16.h>

#define NTOT 65536   // T*H*W

typedef __hip_bfloat16 bf16;

__device__ __forceinline__ float lo2f(unsigned u) { return __uint_as_float(u << 16); }
__device__ __forceinline__ float hi2f(unsigned u) { return __uint_as_float(u & 0xffff0000u); }

// ---------------- K1: 1x1x1 conv  qkv[oc][n] = sum_ic w[oc][ic] * x[ic][n]  (bf16 out)
__global__ __launch_bounds__(256) void k_qkv(const float* __restrict__ x,
                                             const float* __restrict__ w,
                                             bf16* __restrict__ qkv) {
  const int n = blockIdx.x * 256 + threadIdx.x;
  const int oc0 = blockIdx.y * 192;
  float xc[64];
#pragma unroll
  for (int ic = 0; ic < 64; ++ic) xc[ic] = x[ic * NTOT + n];
#pragma unroll 2
  for (int oc = oc0; oc < oc0 + 192; ++oc) {
    const float* wr = w + oc * 64;
    float acc = 0.f;
#pragma unroll
    for (int ic = 0; ic < 64; ++ic) acc = fmaf(wr[ic], xc[ic], acc);
    qkv[oc * NTOT + n] = __float2bfloat16(acc);
  }
}

// ---------------- K2: grouped 3x3x3 conv, 192 groups of 4 in -> 4 out channels
__global__ __launch_bounds__(256) void k_dwconv(const bf16* __restrict__ qkv,
                                                const float* __restrict__ dww,
                                                bf16* __restrict__ out) {
  const int g  = blockIdx.y;        // 0..191
  const int wt = blockIdx.x & 3;    // 4 w-tiles of 16
  const int ht = blockIdx.x >> 2;   // 8 h-tiles of 8
  const int h0 = ht * 8, w0 = wt * 16;
  __shared__ float xs[4 * 18 * 10 * 18];  // [ic][tt18][hh10][ww18]  51.84 KB
  __shared__ float wsm[432];
  const int tid = threadIdx.x;
  if (tid < 216) { wsm[tid] = dww[g * 432 + tid]; wsm[tid + 216] = dww[g * 432 + tid + 216]; }
  const ushort* qsrc = (const ushort*)qkv;
  for (int e = tid; e < 4 * 18 * 10 * 18; e += 256) {
    int ic = e / 3240;
    int r  = e - ic * 3240;
    int tt = r / 180;
    int r2 = r - tt * 180;
    int hh = r2 / 18;
    int ww = r2 - hh * 18;
    int gt = tt - 1, gh = h0 - 1 + hh, gw = w0 - 1 + ww;
    float v = 0.f;
    if ((unsigned)gt < 16u && (unsigned)gh < 64u && (unsigned)gw < 64u)
      v = lo2f(qsrc[(g * 4 + ic) * NTOT + gt * 4096 + gh * 64 + gw]);
    xs[e] = v;
  }
  __syncthreads();
  const int w  = tid & 15;
  const int h  = (tid >> 4) & 7;
  const int ts = tid >> 7;          // 0/1 : t-half
  float acc[4][8];
#pragma unroll
  for (int a = 0; a < 4; ++a)
#pragma unroll
    for (int b = 0; b < 8; ++b) acc[a][b] = 0.f;
#pragma unroll
  for (int ic = 0; ic < 4; ++ic) {
#pragma unroll
    for (int dh = 0; dh < 3; ++dh) {
#pragma unroll
      for (int dw = 0; dw < 3; ++dw) {
        float xcol[10];
#pragma unroll
        for (int j = 0; j < 10; ++j)
          xcol[j] = xs[((ic * 18 + (ts * 8 + j)) * 10 + (h + dh)) * 18 + (w + dw)];
#pragma unroll
        for (int oc = 0; oc < 4; ++oc) {
#pragma unroll
          for (int dt = 0; dt < 3; ++dt) {
            const float wv = wsm[(oc * 4 + ic) * 27 + dt * 9 + dh * 3 + dw];
#pragma unroll
            for (int it = 0; it < 8; ++it)
              acc[oc][it] = fmaf(wv, xcol[it + dt], acc[oc][it]);
          }
        }
      }
    }
  }
#pragma unroll
  for (int oc = 0; oc < 4; ++oc)
#pragma unroll
    for (int it = 0; it < 8; ++it)
      out[(g * 4 + oc) * NTOT + (ts * 8 + it) * 4096 + (h0 + h) * 64 + (w0 + w)] =
          __float2bfloat16(acc[oc][it]);
}

// ---------------- K3: partial gram S[c][d] = sum_n q[c][n]k[d][n], plus sum q^2, k^2
__global__ __launch_bounds__(256) void k_attn_part(const bf16* __restrict__ dwout,
                                                   float* __restrict__ pS,
                                                   float* __restrict__ pQ,
                                                   float* __restrict__ pK) {
  const int head = blockIdx.y;
  const int chunk = blockIdx.x;   // 0..127, each 512 n
  const int tid = threadIdx.x;
  const ushort* qb = (const ushort*)dwout + (head * 64) * (size_t)NTOT;
  const ushort* kb = (const ushort*)dwout + (256 + head * 64) * (size_t)NTOT;
  __shared__ float lq[64][68];   // 17.4 KB
  __shared__ float lk[64][68];
  const int ci = tid & 15, di = tid >> 4;
  float acc[4][4] = {};
  float qq = 0.f, kk = 0.f;
  for (int s = 0; s < 8; ++s) {
    const int nb = chunk * 512 + s * 64;
    __syncthreads();
#pragma unroll
    for (int i = 0; i < 2; ++i) {
      int f = tid + i * 256;      // 0..511
      int c = f >> 3, n8 = f & 7;
      uint4 qv = *(const uint4*)(qb + c * NTOT + nb + n8 * 8);
      uint4 kv = *(const uint4*)(kb + c * NTOT + nb + n8 * 8);
      int r = n8 * 8;
      lq[r + 0][c] = lo2f(qv.x); lq[r + 1][c] = hi2f(qv.x);
      lq[r + 2][c] = lo2f(qv.y); lq[r + 3][c] = hi2f(qv.y);
      lq[r + 4][c] = lo2f(qv.z); lq[r + 5][c] = hi2f(qv.z);
      lq[r + 6][c] = lo2f(qv.w); lq[r + 7][c] = hi2f(qv.w);
      lk[r + 0][c] = lo2f(kv.x); lk[r + 1][c] = hi2f(kv.x);
      lk[r + 2][c] = lo2f(kv.y); lk[r + 3][c] = hi2f(kv.y);
      lk[r + 4][c] = lo2f(kv.z); lk[r + 5][c] = hi2f(kv.z);
      lk[r + 6][c] = lo2f(kv.w); lk[r + 7][c] = hi2f(kv.w);
    }
    __syncthreads();
#pragma unroll 4
    for (int j = 0; j < 64; ++j) {
      float4 q4 = *(const float4*)&lq[j][ci * 4];
      float4 k4 = *(const float4*)&lk[j][di * 4];
      float qa[4] = {q4.x, q4.y, q4.z, q4.w};
      float ka[4] = {k4.x, k4.y, k4.z, k4.w};
#pragma unroll
      for (int a = 0; a < 4; ++a)
#pragma unroll
        for (int b = 0; b < 4; ++b) acc[a][b] = fmaf(qa[a], ka[b], acc[a][b]);
    }
    if (tid < 64) {
#pragma unroll 4
      for (int j = 0; j < 64; ++j) { float v = lq[j][tid]; qq = fmaf(v, v, qq); }
    } else if (tid < 128) {
#pragma unroll 4
      for (int j = 0; j < 64; ++j) { float v = lk[j][tid - 64]; kk = fmaf(v, v, kk); }
    }
  }
  float* ps = pS + (head * 128 + chunk) * 4096;
#pragma unroll
  for (int a = 0; a < 4; ++a) {
    float4 v4 = make_float4(acc[a][0], acc[a][1], acc[a][2], acc[a][3]);
    *(float4*)(ps + (ci * 4 + a) * 64 + di * 4) = v4;
  }
  if (tid < 64) pQ[(head * 128 + chunk) * 64 + tid] = qq;
  else if (tid < 128) pK[(head * 128 + chunk) * 64 + (tid - 64)] = kk;
}

// ---------------- K4a: reduce partials, normalize, temperature, softmax -> A[h][c][d]
__global__ __launch_bounds__(256) void k_softmax(const float* __restrict__ pS,
                                                 const float* __restrict__ pQ,
                                                 const float* __restrict__ pK,
                                                 const float* __restrict__ temp,
                                                 float* __restrict__ A) {
  const int head = blockIdx.x;
  const int tid = threadIdx.x;
  __shared__ float rq[64], rk[64];
  if (tid < 64) {
    float s = 0.f;
    for (int ch = 0; ch < 128; ++ch) s += pQ[(head * 128 + ch) * 64 + tid];
    rq[tid] = 1.f / fmaxf(sqrtf(s), 1e-12f);
  } else if (tid < 128) {
    float s = 0.f;
    for (int ch = 0; ch < 128; ++ch) s += pK[(head * 128 + ch) * 64 + (tid - 64)];
    rk[tid - 64] = 1.f / fmaxf(sqrtf(s), 1e-12f);
  }
  __syncthreads();
  const int c = tid >> 2, r = tid & 3;
  float4 a0 = {0,0,0,0}, a1 = {0,0,0,0}, a2 = {0,0,0,0}, a3 = {0,0,0,0};
  const float* base = pS + head * 128 * 4096 + c * 64 + r * 16;
  for (int ch = 0; ch < 128; ++ch) {
    const float* p = base + ch * 4096;
    float4 b0 = *(const float4*)(p + 0);
    float4 b1 = *(const float4*)(p + 4);
    float4 b2 = *(const float4*)(p + 8);
    float4 b3 = *(const float4*)(p + 12);
    a0.x += b0.x; a0.y += b0.y; a0.z += b0.z; a0.w += b0.w;
    a1.x += b1.x; a1.y += b1.y; a1.z += b1.z; a1.w += b1.w;
    a2.x += b2.x; a2.y += b2.y; a2.z += b2.z; a2.w += b2.w;
    a3.x += b3.x; a3.y += b3.y; a3.z += b3.z; a3.w += b3.w;
  }
  float v[16] = {a0.x, a0.y, a0.z, a0.w, a1.x, a1.y, a1.z, a1.w,
                 a2.x, a2.y, a2.z, a2.w, a3.x, a3.y, a3.z, a3.w};
  const float tmp = temp[head];
  const float rqc = rq[c];
#pragma unroll
  for (int dd = 0; dd < 16; ++dd) v[dd] = v[dd] * rqc * rk[r * 16 + dd] * tmp;
  float m = v[0];
#pragma unroll
  for (int dd = 1; dd < 16; ++dd) m = fmaxf(m, v[dd]);
  m = fmaxf(m, __shfl_xor(m, 1));
  m = fmaxf(m, __shfl_xor(m, 2));
  float s = 0.f;
#pragma unroll
  for (int dd = 0; dd < 16; ++dd) { v[dd] = expf(v[dd] - m); s += v[dd]; }
  s += __shfl_xor(s, 1);
  s += __shfl_xor(s, 2);
  const float inv = 1.f / s;
  float* ao = A + head * 4096 + c * 64 + r * 16;
#pragma unroll
  for (int q4 = 0; q4 < 4; ++q4) {
    float4 o = make_float4(v[q4*4+0]*inv, v[q4*4+1]*inv, v[q4*4+2]*inv, v[q4*4+3]*inv);
    *(float4*)(ao + q4 * 4) = o;
  }
}

// ---------------- K4b: fold proj into attn:  Mt[h*64+d][oc] = sum_c pw[oc][h*64+c]*A[h][c][d]
__global__ __launch_bounds__(64) void k_mt(const float* __restrict__ pw,
                                           const float* __restrict__ A,
                                           float* __restrict__ Mt) {
  const int hd = blockIdx.x;   // 0..255
  const int h = hd >> 6, d = hd & 63;
  const int oc = threadIdx.x;  // 0..63
  float s = 0.f;
  for (int c = 0; c < 64; ++c)
    s = fmaf(pw[oc * 256 + h * 64 + c], A[(h * 64 + c) * 64 + d], s);
  Mt[hd * 64 + oc] = s;
}

// ---------------- K5: y[oc][n] = sum_hd Mt[hd][oc] * v[hd][n]  (PV + proj fused)
__global__ __launch_bounds__(256) void k_pv(const bf16* __restrict__ dwout,
                                            const float* __restrict__ Mt,
                                            float* __restrict__ y) {
  const int n0 = blockIdx.x * 64;
  const ushort* vb = (const ushort*)dwout + 512 * (size_t)NTOT;
  __shared__ float lv[256][64];   // 64 KB
  const int tid = threadIdx.x;
#pragma unroll
  for (int i = 0; i < 8; ++i) {
    int f = tid + i * 256;        // 0..2047
    int hd = f >> 3, n8 = f & 7;
    uint4 v = *(const uint4*)(vb + hd * NTOT + n0 + n8 * 8);
    float4 a = make_float4(lo2f(v.x), hi2f(v.x), lo2f(v.y), hi2f(v.y));
    float4 b = make_float4(lo2f(v.z), hi2f(v.z), lo2f(v.w), hi2f(v.w));
    *(float4*)&lv[hd][n8 * 8]     = a;
    *(float4*)&lv[hd][n8 * 8 + 4] = b;
  }
  __syncthreads();
  const int oci = tid >> 4, ni = tid & 15;
  float acc[4][4] = {};
#pragma unroll 4
  for (int k = 0; k < 256; ++k) {
    float4 mv = *(const float4*)(Mt + k * 64 + oci * 4);
    float4 vv = *(const float4*)&lv[k][ni * 4];
    float ma[4] = {mv.x, mv.y, mv.z, mv.w};
    float va[4] = {vv.x, vv.y, vv.z, vv.w};
#pragma unroll
    for (int a = 0; a < 4; ++a)
#pragma unroll
      for (int b = 0; b < 4; ++b) acc[a][b] = fmaf(ma[a], va[b], acc[a][b]);
  }
#pragma unroll
  for (int a = 0; a < 4; ++a) {
    float4 o = make_float4(acc[a][0], acc[a][1], acc[a][2], acc[a][3]);
    *(float4*)(y + (oci * 4 + a) * NTOT + n0 + ni * 4) = o;
  }
}

extern "C" void kernel_launch(void* const* d_in, const int* in_sizes, int n_in,
                              void* d_out, int out_size, void* d_ws, size_t ws_size,
                              hipStream_t stream) {
  const float* x      = (const float*)d_in[0];
  const float* qkv_w  = (const float*)d_in[1];
  const float* dw_w   = (const float*)d_in[2];
  const float* proj_w = (const float*)d_in[3];
  const float* temp   = (const float*)d_in[4];
  float* out = (float*)d_out;

  char* w8 = (char*)d_ws;
  bf16*  qkv   = (bf16*)(w8);                          // 768*65536 bf16 = 100,663,296 B
  bf16*  dwout = (bf16*)(w8 + 100663296ull);           // 768*65536 bf16 = 100,663,296 B
  float* pS    = (float*)(w8 + 201326592ull);          // 4*128*4096 f32 = 8,388,608 B
  float* pQ    = (float*)(w8 + 209715200ull);          // 32768 f32
  float* pK    = (float*)(w8 + 209846272ull);          // 32768 f32
  float* A     = (float*)(w8 + 209977344ull);          // 16384 f32
  float* Mt    = (float*)(w8 + 210042880ull);          // 16384 f32
  // total 210,108,416 B

  k_qkv<<<dim3(256, 4), 256, 0, stream>>>(x, qkv_w, qkv);
  k_dwconv<<<dim3(32, 192), 256, 0, stream>>>(qkv, dw_w, dwout);
  k_attn_part<<<dim3(128, 4), 256, 0, stream>>>(dwout, pS, pQ, pK);
  k_softmax<<<4, 256, 0, stream>>>(pS, pQ, pK, temp, A);
  k_mt<<<256, 64, 0, stream>>>(proj_w, A, Mt);
  k_pv<<<1024, 256, 0, stream>>>(dwout, Mt, out);
}

// Round 4
// 517.952 us; speedup vs baseline: 1.4982x; 1.4982x over previous
//
#include <hip/hip_runtime.h>
#include <hip/hip_bf16.h>

#define NTOT 65536   // T*H*W

typedef __hip_bfloat16 bf16;

__device__ __forceinline__ float lo2f(unsigned u) { return __uint_as_float(u << 16); }
__device__ __forceinline__ float hi2f(unsigned u) { return __uint_as_float(u & 0xffff0000u); }
__device__ __forceinline__ ushort f2bs(float f) {
  bf16 b = __float2bfloat16(f);
  union { bf16 b; ushort u; } cv;
  cv.b = b;
  return cv.u;
}

// ---------------- K1: 1x1x1 conv as tiled GEMM:  qkv[oc][n] = sum_k w[oc][k] * x[k][n]
// block tile: 64 oc x 64 n, K=64 resident in LDS
__global__ __launch_bounds__(256) void k_qkv(const float* __restrict__ x,
                                             const float* __restrict__ w,
                                             bf16* __restrict__ qkv) {
  const int n0  = blockIdx.x * 64;
  const int oct = blockIdx.y;           // 0..11
  __shared__ float Wt[64][68];          // [k][oc]
  __shared__ float Xs[64][68];          // [k][n]
  const int tid = threadIdx.x;
  const float4* w4 = (const float4*)w;
#pragma unroll
  for (int i = 0; i < 4; ++i) {
    int idx = tid + i * 256;            // 0..1023
    int oc = idx >> 4, kq = idx & 15;
    float4 wv = w4[(oct * 64 + oc) * 16 + kq];
    Wt[kq * 4 + 0][oc] = wv.x;
    Wt[kq * 4 + 1][oc] = wv.y;
    Wt[kq * 4 + 2][oc] = wv.z;
    Wt[kq * 4 + 3][oc] = wv.w;
    int k = idx >> 4, c4 = idx & 15;
    *(float4*)&Xs[k][c4 * 4] = *(const float4*)(x + k * NTOT + n0 + c4 * 4);
  }
  __syncthreads();
  const int oci = tid >> 4, ni = tid & 15;
  float acc[4][4] = {};
#pragma unroll 8
  for (int k = 0; k < 64; ++k) {
    float4 wf = *(const float4*)&Wt[k][oci * 4];
    float4 xf = *(const float4*)&Xs[k][ni * 4];
    float wa[4] = {wf.x, wf.y, wf.z, wf.w};
    float xa[4] = {xf.x, xf.y, xf.z, xf.w};
#pragma unroll
    for (int a = 0; a < 4; ++a)
#pragma unroll
      for (int b = 0; b < 4; ++b) acc[a][b] = fmaf(wa[a], xa[b], acc[a][b]);
  }
#pragma unroll
  for (int a = 0; a < 4; ++a) {
    const int oc = oct * 64 + oci * 4 + a;
    ushort4 o;
    o.x = f2bs(acc[a][0]);
    o.y = f2bs(acc[a][1]);
    o.z = f2bs(acc[a][2]);
    o.w = f2bs(acc[a][3]);
    *(ushort4*)((ushort*)qkv + (size_t)oc * NTOT + n0 + ni * 4) = o;
  }
}

// ---------------- K2: grouped 3x3x3 conv, 192 groups of 4 in -> 4 out channels
__global__ __launch_bounds__(256) void k_dwconv(const bf16* __restrict__ qkv,
                                                const float* __restrict__ dww,
                                                bf16* __restrict__ out) {
  const int g  = blockIdx.y;        // 0..191
  const int wt = blockIdx.x & 3;    // 4 w-tiles of 16
  const int ht = blockIdx.x >> 2;   // 8 h-tiles of 8
  const int h0 = ht * 8, w0 = wt * 16;
  __shared__ float xs[4 * 18 * 10 * 18];  // [ic][tt18][hh10][ww18]  51.84 KB
  __shared__ float wsm[432];
  const int tid = threadIdx.x;
  if (tid < 216) { wsm[tid] = dww[g * 432 + tid]; wsm[tid + 216] = dww[g * 432 + tid + 216]; }
  const ushort* qsrc = (const ushort*)qkv;
  for (int e = tid; e < 4 * 18 * 10 * 18; e += 256) {
    int ic = e / 3240;
    int r  = e - ic * 3240;
    int tt = r / 180;
    int r2 = r - tt * 180;
    int hh = r2 / 18;
    int ww = r2 - hh * 18;
    int gt = tt - 1, gh = h0 - 1 + hh, gw = w0 - 1 + ww;
    float v = 0.f;
    if ((unsigned)gt < 16u && (unsigned)gh < 64u && (unsigned)gw < 64u)
      v = lo2f(qsrc[(g * 4 + ic) * NTOT + gt * 4096 + gh * 64 + gw]);
    xs[e] = v;
  }
  __syncthreads();
  const int w  = tid & 15;
  const int h  = (tid >> 4) & 7;
  const int ts = tid >> 7;          // 0/1 : t-half
  float acc[4][8];
#pragma unroll
  for (int a = 0; a < 4; ++a)
#pragma unroll
    for (int b = 0; b < 8; ++b) acc[a][b] = 0.f;
#pragma unroll
  for (int ic = 0; ic < 4; ++ic) {
#pragma unroll
    for (int dh = 0; dh < 3; ++dh) {
#pragma unroll
      for (int dw = 0; dw < 3; ++dw) {
        float xcol[10];
#pragma unroll
        for (int j = 0; j < 10; ++j)
          xcol[j] = xs[((ic * 18 + (ts * 8 + j)) * 10 + (h + dh)) * 18 + (w + dw)];
#pragma unroll
        for (int oc = 0; oc < 4; ++oc) {
#pragma unroll
          for (int dt = 0; dt < 3; ++dt) {
            const float wv = wsm[(oc * 4 + ic) * 27 + dt * 9 + dh * 3 + dw];
#pragma unroll
            for (int it = 0; it < 8; ++it)
              acc[oc][it] = fmaf(wv, xcol[it + dt], acc[oc][it]);
          }
        }
      }
    }
  }
#pragma unroll
  for (int oc = 0; oc < 4; ++oc)
#pragma unroll
    for (int it = 0; it < 8; ++it)
      out[(g * 4 + oc) * NTOT + (ts * 8 + it) * 4096 + (h0 + h) * 64 + (w0 + w)] =
          __float2bfloat16(acc[oc][it]);
}

// ---------------- K3: partial gram S[c][d] = sum_n q[c][n]k[d][n], plus sum q^2, k^2
__global__ __launch_bounds__(256) void k_attn_part(const bf16* __restrict__ dwout,
                                                   float* __restrict__ pS,
                                                   float* __restrict__ pQ,
                                                   float* __restrict__ pK) {
  const int head = blockIdx.y;
  const int chunk = blockIdx.x;   // 0..127, each 512 n
  const int tid = threadIdx.x;
  const ushort* qb = (const ushort*)dwout + (head * 64) * (size_t)NTOT;
  const ushort* kb = (const ushort*)dwout + (256 + head * 64) * (size_t)NTOT;
  __shared__ float lq[64][68];   // 17.4 KB
  __shared__ float lk[64][68];
  const int ci = tid & 15, di = tid >> 4;
  float acc[4][4] = {};
  float qq = 0.f, kk = 0.f;
  for (int s = 0; s < 8; ++s) {
    const int nb = chunk * 512 + s * 64;
    __syncthreads();
#pragma unroll
    for (int i = 0; i < 2; ++i) {
      int f = tid + i * 256;      // 0..511
      int c = f >> 3, n8 = f & 7;
      uint4 qv = *(const uint4*)(qb + c * NTOT + nb + n8 * 8);
      uint4 kv = *(const uint4*)(kb + c * NTOT + nb + n8 * 8);
      int r = n8 * 8;
      lq[r + 0][c] = lo2f(qv.x); lq[r + 1][c] = hi2f(qv.x);
      lq[r + 2][c] = lo2f(qv.y); lq[r + 3][c] = hi2f(qv.y);
      lq[r + 4][c] = lo2f(qv.z); lq[r + 5][c] = hi2f(qv.z);
      lq[r + 6][c] = lo2f(qv.w); lq[r + 7][c] = hi2f(qv.w);
      lk[r + 0][c] = lo2f(kv.x); lk[r + 1][c] = hi2f(kv.x);
      lk[r + 2][c] = lo2f(kv.y); lk[r + 3][c] = hi2f(kv.y);
      lk[r + 4][c] = lo2f(kv.z); lk[r + 5][c] = hi2f(kv.z);
      lk[r + 6][c] = lo2f(kv.w); lk[r + 7][c] = hi2f(kv.w);
    }
    __syncthreads();
#pragma unroll 4
    for (int j = 0; j < 64; ++j) {
      float4 q4 = *(const float4*)&lq[j][ci * 4];
      float4 k4 = *(const float4*)&lk[j][di * 4];
      float qa[4] = {q4.x, q4.y, q4.z, q4.w};
      float ka[4] = {k4.x, k4.y, k4.z, k4.w};
#pragma unroll
      for (int a = 0; a < 4; ++a)
#pragma unroll
        for (int b = 0; b < 4; ++b) acc[a][b] = fmaf(qa[a], ka[b], acc[a][b]);
    }
    if (tid < 64) {
#pragma unroll 4
      for (int j = 0; j < 64; ++j) { float v = lq[j][tid]; qq = fmaf(v, v, qq); }
    } else if (tid < 128) {
#pragma unroll 4
      for (int j = 0; j < 64; ++j) { float v = lk[j][tid - 64]; kk = fmaf(v, v, kk); }
    }
  }
  float* ps = pS + (head * 128 + chunk) * 4096;
#pragma unroll
  for (int a = 0; a < 4; ++a) {
    float4 v4 = make_float4(acc[a][0], acc[a][1], acc[a][2], acc[a][3]);
    *(float4*)(ps + (ci * 4 + a) * 64 + di * 4) = v4;
  }
  if (tid < 64) pQ[(head * 128 + chunk) * 64 + tid] = qq;
  else if (tid < 128) pK[(head * 128 + chunk) * 64 + (tid - 64)] = kk;
}

// ---------------- K4a: reduce partials, normalize, temperature, softmax -> A[h][c][d]
__global__ __launch_bounds__(256) void k_softmax(const float* __restrict__ pS,
                                                 const float* __restrict__ pQ,
                                                 const float* __restrict__ pK,
                                                 const float* __restrict__ temp,
                                                 float* __restrict__ A) {
  const int head = blockIdx.x;
  const int tid = threadIdx.x;
  __shared__ float rq[64], rk[64];
  if (tid < 64) {
    float s = 0.f;
    for (int ch = 0; ch < 128; ++ch) s += pQ[(head * 128 + ch) * 64 + tid];
    rq[tid] = 1.f / fmaxf(sqrtf(s), 1e-12f);
  } else if (tid < 128) {
    float s = 0.f;
    for (int ch = 0; ch < 128; ++ch) s += pK[(head * 128 + ch) * 64 + (tid - 64)];
    rk[tid - 64] = 1.f / fmaxf(sqrtf(s), 1e-12f);
  }
  __syncthreads();
  const int c = tid >> 2, r = tid & 3;
  float4 a0 = {0,0,0,0}, a1 = {0,0,0,0}, a2 = {0,0,0,0}, a3 = {0,0,0,0};
  const float* base = pS + head * 128 * 4096 + c * 64 + r * 16;
  for (int ch = 0; ch < 128; ++ch) {
    const float* p = base + ch * 4096;
    float4 b0 = *(const float4*)(p + 0);
    float4 b1 = *(const float4*)(p + 4);
    float4 b2 = *(const float4*)(p + 8);
    float4 b3 = *(const float4*)(p + 12);
    a0.x += b0.x; a0.y += b0.y; a0.z += b0.z; a0.w += b0.w;
    a1.x += b1.x; a1.y += b1.y; a1.z += b1.z; a1.w += b1.w;
    a2.x += b2.x; a2.y += b2.y; a2.z += b2.z; a2.w += b2.w;
    a3.x += b3.x; a3.y += b3.y; a3.z += b3.z; a3.w += b3.w;
  }
  float v[16] = {a0.x, a0.y, a0.z, a0.w, a1.x, a1.y, a1.z, a1.w,
                 a2.x, a2.y, a2.z, a2.w, a3.x, a3.y, a3.z, a3.w};
  const float tmp = temp[head];
  const float rqc = rq[c];
#pragma unroll
  for (int dd = 0; dd < 16; ++dd) v[dd] = v[dd] * rqc * rk[r * 16 + dd] * tmp;
  float m = v[0];
#pragma unroll
  for (int dd = 1; dd < 16; ++dd) m = fmaxf(m, v[dd]);
  m = fmaxf(m, __shfl_xor(m, 1));
  m = fmaxf(m, __shfl_xor(m, 2));
  float s = 0.f;
#pragma unroll
  for (int dd = 0; dd < 16; ++dd) { v[dd] = expf(v[dd] - m); s += v[dd]; }
  s += __shfl_xor(s, 1);
  s += __shfl_xor(s, 2);
  const float inv = 1.f / s;
  float* ao = A + head * 4096 + c * 64 + r * 16;
#pragma unroll
  for (int q4 = 0; q4 < 4; ++q4) {
    float4 o = make_float4(v[q4*4+0]*inv, v[q4*4+1]*inv, v[q4*4+2]*inv, v[q4*4+3]*inv);
    *(float4*)(ao + q4 * 4) = o;
  }
}

// ---------------- K4b: fold proj into attn:  Mt[h*64+d][oc] = sum_c pw[oc][h*64+c]*A[h][c][d]
__global__ __launch_bounds__(64) void k_mt(const float* __restrict__ pw,
                                           const float* __restrict__ A,
                                           float* __restrict__ Mt) {
  const int hd = blockIdx.x;   // 0..255
  const int h = hd >> 6, d = hd & 63;
  const int oc = threadIdx.x;  // 0..63
  float s = 0.f;
  for (int c = 0; c < 64; ++c)
    s = fmaf(pw[oc * 256 + h * 64 + c], A[(h * 64 + c) * 64 + d], s);
  Mt[hd * 64 + oc] = s;
}

// ---------------- K5: y[oc][n] = sum_hd Mt[hd][oc] * v[hd][n]  (PV + proj fused)
__global__ __launch_bounds__(256) void k_pv(const bf16* __restrict__ dwout,
                                            const float* __restrict__ Mt,
                                            float* __restrict__ y) {
  const int n0 = blockIdx.x * 64;
  const ushort* vb = (const ushort*)dwout + 512 * (size_t)NTOT;
  __shared__ float lv[256][64];   // 64 KB
  const int tid = threadIdx.x;
#pragma unroll
  for (int i = 0; i < 8; ++i) {
    int f = tid + i * 256;        // 0..2047
    int hd = f >> 3, n8 = f & 7;
    uint4 v = *(const uint4*)(vb + hd * NTOT + n0 + n8 * 8);
    float4 a = make_float4(lo2f(v.x), hi2f(v.x), lo2f(v.y), hi2f(v.y));
    float4 b = make_float4(lo2f(v.z), hi2f(v.z), lo2f(v.w), hi2f(v.w));
    *(float4*)&lv[hd][n8 * 8]     = a;
    *(float4*)&lv[hd][n8 * 8 + 4] = b;
  }
  __syncthreads();
  const int oci = tid >> 4, ni = tid & 15;
  float acc[4][4] = {};
#pragma unroll 4
  for (int k = 0; k < 256; ++k) {
    float4 mv = *(const float4*)(Mt + k * 64 + oci * 4);
    float4 vv = *(const float4*)&lv[k][ni * 4];
    float ma[4] = {mv.x, mv.y, mv.z, mv.w};
    float va[4] = {vv.x, vv.y, vv.z, vv.w};
#pragma unroll
    for (int a = 0; a < 4; ++a)
#pragma unroll
      for (int b = 0; b < 4; ++b) acc[a][b] = fmaf(ma[a], va[b], acc[a][b]);
  }
#pragma unroll
  for (int a = 0; a < 4; ++a) {
    float4 o = make_float4(acc[a][0], acc[a][1], acc[a][2], acc[a][3]);
    *(float4*)(y + (oci * 4 + a) * NTOT + n0 + ni * 4) = o;
  }
}

extern "C" void kernel_launch(void* const* d_in, const int* in_sizes, int n_in,
                              void* d_out, int out_size, void* d_ws, size_t ws_size,
                              hipStream_t stream) {
  const float* x      = (const float*)d_in[0];
  const float* qkv_w  = (const float*)d_in[1];
  const float* dw_w   = (const float*)d_in[2];
  const float* proj_w = (const float*)d_in[3];
  const float* temp   = (const float*)d_in[4];
  float* out = (float*)d_out;

  char* w8 = (char*)d_ws;
  bf16*  qkv   = (bf16*)(w8);                          // 768*65536 bf16 = 100,663,296 B
  bf16*  dwout = (bf16*)(w8 + 100663296ull);           // 768*65536 bf16 = 100,663,296 B
  float* pS    = (float*)(w8 + 201326592ull);          // 4*128*4096 f32 = 8,388,608 B
  float* pQ    = (float*)(w8 + 209715200ull);          // 32768 f32
  float* pK    = (float*)(w8 + 209846272ull);          // 32768 f32
  float* A     = (float*)(w8 + 209977344ull);          // 16384 f32
  float* Mt    = (float*)(w8 + 210042880ull);          // 16384 f32
  // total 210,108,416 B

  k_qkv<<<dim3(1024, 12), 256, 0, stream>>>(x, qkv_w, qkv);
  k_dwconv<<<dim3(32, 192), 256, 0, stream>>>(qkv, dw_w, dwout);
  k_attn_part<<<dim3(128, 4), 256, 0, stream>>>(dwout, pS, pQ, pK);
  k_softmax<<<4, 256, 0, stream>>>(pS, pQ, pK, temp, A);
  k_mt<<<256, 64, 0, stream>>>(proj_w, A, Mt);
  k_pv<<<1024, 256, 0, stream>>>(dwout, Mt, out);
}

// Round 5
// 467.102 us; speedup vs baseline: 1.6613x; 1.1089x over previous
//
#include <hip/hip_runtime.h>
#include <hip/hip_bf16.h>

#define NTOT 65536   // T*H*W

typedef __hip_bfloat16 bf16;

__device__ __forceinline__ float lo2f(unsigned u) { return __uint_as_float(u << 16); }
__device__ __forceinline__ float hi2f(unsigned u) { return __uint_as_float(u & 0xffff0000u); }
__device__ __forceinline__ ushort f2bs(float f) {
  bf16 b = __float2bfloat16(f);
  union { bf16 b; ushort u; } cv;
  cv.b = b;
  return cv.u;
}

// ---------------- K1: 1x1x1 conv as tiled GEMM:  qkv[oc][n] = sum_k w[oc][k] * x[k][n]
__global__ __launch_bounds__(256) void k_qkv(const float* __restrict__ x,
                                             const float* __restrict__ w,
                                             bf16* __restrict__ qkv) {
  const int n0  = blockIdx.x * 64;
  const int oct = blockIdx.y;           // 0..11
  __shared__ float Wt[64][68];          // [k][oc]
  __shared__ float Xs[64][68];          // [k][n]
  const int tid = threadIdx.x;
  const float4* w4 = (const float4*)w;
#pragma unroll
  for (int i = 0; i < 4; ++i) {
    int idx = tid + i * 256;            // 0..1023
    int oc = idx >> 4, kq = idx & 15;
    float4 wv = w4[(oct * 64 + oc) * 16 + kq];
    Wt[kq * 4 + 0][oc] = wv.x;
    Wt[kq * 4 + 1][oc] = wv.y;
    Wt[kq * 4 + 2][oc] = wv.z;
    Wt[kq * 4 + 3][oc] = wv.w;
    int k = idx >> 4, c4 = idx & 15;
    *(float4*)&Xs[k][c4 * 4] = *(const float4*)(x + k * NTOT + n0 + c4 * 4);
  }
  __syncthreads();
  const int oci = tid >> 4, ni = tid & 15;
  float acc[4][4] = {};
#pragma unroll 8
  for (int k = 0; k < 64; ++k) {
    float4 wf = *(const float4*)&Wt[k][oci * 4];
    float4 xf = *(const float4*)&Xs[k][ni * 4];
    float wa[4] = {wf.x, wf.y, wf.z, wf.w};
    float xa[4] = {xf.x, xf.y, xf.z, xf.w};
#pragma unroll
    for (int a = 0; a < 4; ++a)
#pragma unroll
      for (int b = 0; b < 4; ++b) acc[a][b] = fmaf(wa[a], xa[b], acc[a][b]);
  }
#pragma unroll
  for (int a = 0; a < 4; ++a) {
    const int oc = oct * 64 + oci * 4 + a;
    ushort4 o;
    o.x = f2bs(acc[a][0]);
    o.y = f2bs(acc[a][1]);
    o.z = f2bs(acc[a][2]);
    o.w = f2bs(acc[a][3]);
    *(ushort4*)((ushort*)qkv + (size_t)oc * NTOT + n0 + ni * 4) = o;
  }
}

// ---------------- K2: grouped 3x3x3 conv, 192 groups of 4 in -> 4 out channels
// bf16 LDS x-tile, t-contiguous [ic][hh10][ww18][tt20]; weights [ic][dh][dw][oc*4+dt]
__global__ __launch_bounds__(256) void k_dwconv(const bf16* __restrict__ qkv,
                                                const float* __restrict__ dww,
                                                bf16* __restrict__ out) {
  const int g  = blockIdx.y;        // 0..191
  const int wt = blockIdx.x & 3;    // 4 w-tiles of 16
  const int ht = blockIdx.x >> 2;   // 8 h-tiles of 8
  const int h0 = ht * 8, w0 = wt * 16;
  __shared__ ushort xs[4 * 10 * 18 * 20];   // 28.8 KB, t-index = global t + 1
  __shared__ float  wsm[4 * 3 * 3 * 16];    // 2.3 KB  [ic][dh][dw][oc*4+dt]
  const int tid = threadIdx.x;
  // weights
  for (int idx = tid; idx < 576; idx += 256) {
    int s  = idx & 15;
    int oc = s >> 2, dt = s & 3;
    int rest = idx >> 4;
    int dw = rest % 3;
    int dh = (rest / 3) % 3;
    int ic = rest / 9;
    float v = 0.f;
    if (dt < 3) v = dww[g * 432 + (oc * 4 + ic) * 27 + dt * 9 + dh * 3 + dw];
    wsm[idx] = v;
  }
  // x tile: e = ((ic*10 + hh)*18 + tt)*18 + ww  (ww fastest for coalescing)
  const ushort* qsrc = (const ushort*)qkv;
  for (int e = tid; e < 4 * 10 * 18 * 18; e += 256) {
    int ww = e % 18;
    int r  = e / 18;
    int tt = r % 18;
    int r2 = r / 18;
    int hh = r2 % 10;
    int ic = r2 / 10;
    int gt = tt - 1, gh = h0 - 1 + hh, gw = w0 - 1 + ww;
    ushort v = 0;
    if ((unsigned)gt < 16u && (unsigned)gh < 64u && (unsigned)gw < 64u)
      v = qsrc[(g * 4 + ic) * NTOT + gt * 4096 + gh * 64 + gw];
    xs[((ic * 10 + hh) * 18 + ww) * 20 + tt] = v;
  }
  __syncthreads();
  const int w  = tid & 15;
  const int h  = (tid >> 4) & 7;
  const int ts = tid >> 7;          // 0/1 : t-half
  float acc[4][8];
#pragma unroll
  for (int a = 0; a < 4; ++a)
#pragma unroll
    for (int b = 0; b < 8; ++b) acc[a][b] = 0.f;
#pragma unroll 1
  for (int ic = 0; ic < 4; ++ic) {
    const ushort* xsl = xs + ic * 3600 + ts * 8;
    const float*  wsl = wsm + ic * 144;
#pragma unroll
    for (int dh = 0; dh < 3; ++dh) {
#pragma unroll
      for (int dw = 0; dw < 3; ++dw) {
        const ushort* col = xsl + ((h + dh) * 18 + (w + dw)) * 20;
        uint2 p0 = *(const uint2*)(col);       // t0..3
        uint2 p1 = *(const uint2*)(col + 4);   // t4..7
        uint  p2 = *(const uint*)(col + 8);    // t8..9
        float xc[10];
        xc[0] = lo2f(p0.x); xc[1] = hi2f(p0.x);
        xc[2] = lo2f(p0.y); xc[3] = hi2f(p0.y);
        xc[4] = lo2f(p1.x); xc[5] = hi2f(p1.x);
        xc[6] = lo2f(p1.y); xc[7] = hi2f(p1.y);
        xc[8] = lo2f(p2);   xc[9] = hi2f(p2);
        const float4* wp = (const float4*)(wsl + (dh * 3 + dw) * 16);
        float4 wv[4] = {wp[0], wp[1], wp[2], wp[3]};   // wv[oc] = {dt0,dt1,dt2,pad}
#pragma unroll
        for (int oc = 0; oc < 4; ++oc) {
          float w0 = wv[oc].x, w1 = wv[oc].y, w2 = wv[oc].z;
#pragma unroll
          for (int it = 0; it < 8; ++it)
            acc[oc][it] = fmaf(w0, xc[it],
                          fmaf(w1, xc[it + 1],
                          fmaf(w2, xc[it + 2], acc[oc][it])));
        }
      }
    }
  }
#pragma unroll
  for (int oc = 0; oc < 4; ++oc)
#pragma unroll
    for (int it = 0; it < 8; ++it)
      out[(g * 4 + oc) * NTOT + (ts * 8 + it) * 4096 + (h0 + h) * 64 + (w0 + w)] =
          __float2bfloat16(acc[oc][it]);
}

// ---------------- K3: partial gram S[c][d] = sum_n q[c][n]k[d][n], plus sum q^2, k^2
__global__ __launch_bounds__(256) void k_attn_part(const bf16* __restrict__ dwout,
                                                   float* __restrict__ pS,
                                                   float* __restrict__ pQ,
                                                   float* __restrict__ pK) {
  const int head = blockIdx.y;
  const int chunk = blockIdx.x;   // 0..127, each 512 n
  const int tid = threadIdx.x;
  const ushort* qb = (const ushort*)dwout + (head * 64) * (size_t)NTOT;
  const ushort* kb = (const ushort*)dwout + (256 + head * 64) * (size_t)NTOT;
  __shared__ float lq[64][68];   // 17.4 KB
  __shared__ float lk[64][68];
  const int ci = tid & 15, di = tid >> 4;
  float acc[4][4] = {};
  float qq = 0.f, kk = 0.f;
  for (int s = 0; s < 8; ++s) {
    const int nb = chunk * 512 + s * 64;
    __syncthreads();
#pragma unroll
    for (int i = 0; i < 2; ++i) {
      int f = tid + i * 256;      // 0..511
      int c = f >> 3, n8 = f & 7;
      uint4 qv = *(const uint4*)(qb + c * NTOT + nb + n8 * 8);
      uint4 kv = *(const uint4*)(kb + c * NTOT + nb + n8 * 8);
      int r = n8 * 8;
      lq[r + 0][c] = lo2f(qv.x); lq[r + 1][c] = hi2f(qv.x);
      lq[r + 2][c] = lo2f(qv.y); lq[r + 3][c] = hi2f(qv.y);
      lq[r + 4][c] = lo2f(qv.z); lq[r + 5][c] = hi2f(qv.z);
      lq[r + 6][c] = lo2f(qv.w); lq[r + 7][c] = hi2f(qv.w);
      lk[r + 0][c] = lo2f(kv.x); lk[r + 1][c] = hi2f(kv.x);
      lk[r + 2][c] = lo2f(kv.y); lk[r + 3][c] = hi2f(kv.y);
      lk[r + 4][c] = lo2f(kv.z); lk[r + 5][c] = hi2f(kv.z);
      lk[r + 6][c] = lo2f(kv.w); lk[r + 7][c] = hi2f(kv.w);
    }
    __syncthreads();
#pragma unroll 4
    for (int j = 0; j < 64; ++j) {
      float4 q4 = *(const float4*)&lq[j][ci * 4];
      float4 k4 = *(const float4*)&lk[j][di * 4];
      float qa[4] = {q4.x, q4.y, q4.z, q4.w};
      float ka[4] = {k4.x, k4.y, k4.z, k4.w};
#pragma unroll
      for (int a = 0; a < 4; ++a)
#pragma unroll
        for (int b = 0; b < 4; ++b) acc[a][b] = fmaf(qa[a], ka[b], acc[a][b]);
    }
    if (tid < 64) {
#pragma unroll 4
      for (int j = 0; j < 64; ++j) { float v = lq[j][tid]; qq = fmaf(v, v, qq); }
    } else if (tid < 128) {
#pragma unroll 4
      for (int j = 0; j < 64; ++j) { float v = lk[j][tid - 64]; kk = fmaf(v, v, kk); }
    }
  }
  float* ps = pS + (head * 128 + chunk) * 4096;
#pragma unroll
  for (int a = 0; a < 4; ++a) {
    float4 v4 = make_float4(acc[a][0], acc[a][1], acc[a][2], acc[a][3]);
    *(float4*)(ps + (ci * 4 + a) * 64 + di * 4) = v4;
  }
  if (tid < 64) pQ[(head * 128 + chunk) * 64 + tid] = qq;
  else if (tid < 128) pK[(head * 128 + chunk) * 64 + (tid - 64)] = kk;
}

// ---------------- K4a: reduce partials, normalize, temperature, softmax -> A[h][c][d]
__global__ __launch_bounds__(256) void k_softmax(const float* __restrict__ pS,
                                                 const float* __restrict__ pQ,
                                                 const float* __restrict__ pK,
                                                 const float* __restrict__ temp,
                                                 float* __restrict__ A) {
  const int head = blockIdx.x;
  const int tid = threadIdx.x;
  __shared__ float rq[64], rk[64];
  if (tid < 64) {
    float s = 0.f;
    for (int ch = 0; ch < 128; ++ch) s += pQ[(head * 128 + ch) * 64 + tid];
    rq[tid] = 1.f / fmaxf(sqrtf(s), 1e-12f);
  } else if (tid < 128) {
    float s = 0.f;
    for (int ch = 0; ch < 128; ++ch) s += pK[(head * 128 + ch) * 64 + (tid - 64)];
    rk[tid - 64] = 1.f / fmaxf(sqrtf(s), 1e-12f);
  }
  __syncthreads();
  const int c = tid >> 2, r = tid & 3;
  float4 a0 = {0,0,0,0}, a1 = {0,0,0,0}, a2 = {0,0,0,0}, a3 = {0,0,0,0};
  const float* base = pS + head * 128 * 4096 + c * 64 + r * 16;
  for (int ch = 0; ch < 128; ++ch) {
    const float* p = base + ch * 4096;
    float4 b0 = *(const float4*)(p + 0);
    float4 b1 = *(const float4*)(p + 4);
    float4 b2 = *(const float4*)(p + 8);
    float4 b3 = *(const float4*)(p + 12);
    a0.x += b0.x; a0.y += b0.y; a0.z += b0.z; a0.w += b0.w;
    a1.x += b1.x; a1.y += b1.y; a1.z += b1.z; a1.w += b1.w;
    a2.x += b2.x; a2.y += b2.y; a2.z += b2.z; a2.w += b2.w;
    a3.x += b3.x; a3.y += b3.y; a3.z += b3.z; a3.w += b3.w;
  }
  float v[16] = {a0.x, a0.y, a0.z, a0.w, a1.x, a1.y, a1.z, a1.w,
                 a2.x, a2.y, a2.z, a2.w, a3.x, a3.y, a3.z, a3.w};
  const float tmp = temp[head];
  const float rqc = rq[c];
#pragma unroll
  for (int dd = 0; dd < 16; ++dd) v[dd] = v[dd] * rqc * rk[r * 16 + dd] * tmp;
  float m = v[0];
#pragma unroll
  for (int dd = 1; dd < 16; ++dd) m = fmaxf(m, v[dd]);
  m = fmaxf(m, __shfl_xor(m, 1));
  m = fmaxf(m, __shfl_xor(m, 2));
  float s = 0.f;
#pragma unroll
  for (int dd = 0; dd < 16; ++dd) { v[dd] = expf(v[dd] - m); s += v[dd]; }
  s += __shfl_xor(s, 1);
  s += __shfl_xor(s, 2);
  const float inv = 1.f / s;
  float* ao = A + head * 4096 + c * 64 + r * 16;
#pragma unroll
  for (int q4 = 0; q4 < 4; ++q4) {
    float4 o = make_float4(v[q4*4+0]*inv, v[q4*4+1]*inv, v[q4*4+2]*inv, v[q4*4+3]*inv);
    *(float4*)(ao + q4 * 4) = o;
  }
}

// ---------------- K4b: fold proj into attn:  Mt[h*64+d][oc] = sum_c pw[oc][h*64+c]*A[h][c][d]
__global__ __launch_bounds__(64) void k_mt(const float* __restrict__ pw,
                                           const float* __restrict__ A,
                                           float* __restrict__ Mt) {
  const int hd = blockIdx.x;   // 0..255
  const int h = hd >> 6, d = hd & 63;
  const int oc = threadIdx.x;  // 0..63
  float s = 0.f;
  for (int c = 0; c < 64; ++c)
    s = fmaf(pw[oc * 256 + h * 64 + c], A[(h * 64 + c) * 64 + d], s);
  Mt[hd * 64 + oc] = s;
}

// ---------------- K5: y[oc][n] = sum_hd Mt[hd][oc] * v[hd][n]  (PV + proj fused)
__global__ __launch_bounds__(256) void k_pv(const bf16* __restrict__ dwout,
                                            const float* __restrict__ Mt,
                                            float* __restrict__ y) {
  const int n0 = blockIdx.x * 64;
  const ushort* vb = (const ushort*)dwout + 512 * (size_t)NTOT;
  __shared__ float lv[256][64];   // 64 KB
  const int tid = threadIdx.x;
#pragma unroll
  for (int i = 0; i < 8; ++i) {
    int f = tid + i * 256;        // 0..2047
    int hd = f >> 3, n8 = f & 7;
    uint4 v = *(const uint4*)(vb + hd * NTOT + n0 + n8 * 8);
    float4 a = make_float4(lo2f(v.x), hi2f(v.x), lo2f(v.y), hi2f(v.y));
    float4 b = make_float4(lo2f(v.z), hi2f(v.z), lo2f(v.w), hi2f(v.w));
    *(float4*)&lv[hd][n8 * 8]     = a;
    *(float4*)&lv[hd][n8 * 8 + 4] = b;
  }
  __syncthreads();
  const int oci = tid >> 4, ni = tid & 15;
  float acc[4][4] = {};
#pragma unroll 4
  for (int k = 0; k < 256; ++k) {
    float4 mv = *(const float4*)(Mt + k * 64 + oci * 4);
    float4 vv = *(const float4*)&lv[k][ni * 4];
    float ma[4] = {mv.x, mv.y, mv.z, mv.w};
    float va[4] = {vv.x, vv.y, vv.z, vv.w};
#pragma unroll
    for (int a = 0; a < 4; ++a)
#pragma unroll
      for (int b = 0; b < 4; ++b) acc[a][b] = fmaf(ma[a], va[b], acc[a][b]);
  }
#pragma unroll
  for (int a = 0; a < 4; ++a) {
    float4 o = make_float4(acc[a][0], acc[a][1], acc[a][2], acc[a][3]);
    *(float4*)(y + (oci * 4 + a) * NTOT + n0 + ni * 4) = o;
  }
}

extern "C" void kernel_launch(void* const* d_in, const int* in_sizes, int n_in,
                              void* d_out, int out_size, void* d_ws, size_t ws_size,
                              hipStream_t stream) {
  const float* x      = (const float*)d_in[0];
  const float* qkv_w  = (const float*)d_in[1];
  const float* dw_w   = (const float*)d_in[2];
  const float* proj_w = (const float*)d_in[3];
  const float* temp   = (const float*)d_in[4];
  float* out = (float*)d_out;

  char* w8 = (char*)d_ws;
  bf16*  qkv   = (bf16*)(w8);                          // 768*65536 bf16 = 100,663,296 B
  bf16*  dwout = (bf16*)(w8 + 100663296ull);           // 768*65536 bf16 = 100,663,296 B
  float* pS    = (float*)(w8 + 201326592ull);          // 4*128*4096 f32 = 8,388,608 B
  float* pQ    = (float*)(w8 + 209715200ull);          // 32768 f32
  float* pK    = (float*)(w8 + 209846272ull);          // 32768 f32
  float* A     = (float*)(w8 + 209977344ull);          // 16384 f32
  float* Mt    = (float*)(w8 + 210042880ull);          // 16384 f32
  // total 210,108,416 B

  k_qkv<<<dim3(1024, 12), 256, 0, stream>>>(x, qkv_w, qkv);
  k_dwconv<<<dim3(32, 192), 256, 0, stream>>>(qkv, dw_w, dwout);
  k_attn_part<<<dim3(128, 4), 256, 0, stream>>>(dwout, pS, pQ, pK);
  k_softmax<<<4, 256, 0, stream>>>(pS, pQ, pK, temp, A);
  k_mt<<<256, 64, 0, stream>>>(proj_w, A, Mt);
  k_pv<<<1024, 256, 0, stream>>>(dwout, Mt, out);
}

// Round 6
// 447.366 us; speedup vs baseline: 1.7346x; 1.0441x over previous
//
#include <hip/hip_runtime.h>
#include <hip/hip_bf16.h>

#define NTOT 65536   // T*H*W

typedef __hip_bfloat16 bf16;

__device__ __forceinline__ float lo2f(unsigned u) { return __uint_as_float(u << 16); }
__device__ __forceinline__ float hi2f(unsigned u) { return __uint_as_float(u & 0xffff0000u); }
__device__ __forceinline__ ushort f2bs(float f) {
  bf16 b = __float2bfloat16(f);
  union { bf16 b; ushort u; } cv;
  cv.b = b;
  return cv.u;
}

// ---------------- K1: 1x1x1 conv as tiled GEMM:  qkv[oc][n] = sum_k w[oc][k] * x[k][n]
__global__ __launch_bounds__(256) void k_qkv(const float* __restrict__ x,
                                             const float* __restrict__ w,
                                             bf16* __restrict__ qkv) {
  const int n0  = blockIdx.x * 64;
  const int oct = blockIdx.y;           // 0..11
  __shared__ float Wt[64][68];          // [k][oc]
  __shared__ float Xs[64][68];          // [k][n]
  const int tid = threadIdx.x;
  const float4* w4 = (const float4*)w;
#pragma unroll
  for (int i = 0; i < 4; ++i) {
    int idx = tid + i * 256;            // 0..1023
    int oc = idx >> 4, kq = idx & 15;
    float4 wv = w4[(oct * 64 + oc) * 16 + kq];
    Wt[kq * 4 + 0][oc] = wv.x;
    Wt[kq * 4 + 1][oc] = wv.y;
    Wt[kq * 4 + 2][oc] = wv.z;
    Wt[kq * 4 + 3][oc] = wv.w;
    int k = idx >> 4, c4 = idx & 15;
    *(float4*)&Xs[k][c4 * 4] = *(const float4*)(x + k * NTOT + n0 + c4 * 4);
  }
  __syncthreads();
  const int oci = tid >> 4, ni = tid & 15;
  float acc[4][4] = {};
#pragma unroll 8
  for (int k = 0; k < 64; ++k) {
    float4 wf = *(const float4*)&Wt[k][oci * 4];
    float4 xf = *(const float4*)&Xs[k][ni * 4];
    float wa[4] = {wf.x, wf.y, wf.z, wf.w};
    float xa[4] = {xf.x, xf.y, xf.z, xf.w};
#pragma unroll
    for (int a = 0; a < 4; ++a)
#pragma unroll
      for (int b = 0; b < 4; ++b) acc[a][b] = fmaf(wa[a], xa[b], acc[a][b]);
  }
#pragma unroll
  for (int a = 0; a < 4; ++a) {
    const int oc = oct * 64 + oci * 4 + a;
    ushort4 o;
    o.x = f2bs(acc[a][0]);
    o.y = f2bs(acc[a][1]);
    o.z = f2bs(acc[a][2]);
    o.w = f2bs(acc[a][3]);
    *(ushort4*)((ushort*)qkv + (size_t)oc * NTOT + n0 + ni * 4) = o;
  }
}

// ---------------- K2: grouped 3x3x3 conv, 192 groups of 4 in -> 4 out channels
// ic phased 2-at-a-time: LDS 16.7 KB -> 8 blocks/CU for latency hiding
__global__ __launch_bounds__(256) void k_dwconv(const bf16* __restrict__ qkv,
                                                const float* __restrict__ dww,
                                                bf16* __restrict__ out) {
  const int g  = blockIdx.y;        // 0..191
  const int wt = blockIdx.x & 3;    // 4 w-tiles of 16
  const int ht = blockIdx.x >> 2;   // 8 h-tiles of 8
  const int h0 = ht * 8, w0 = wt * 16;
  __shared__ ushort xs[2 * 10 * 18 * 20];   // 14.4 KB, 2 ic per phase, t-index = t + 1
  __shared__ float  wsm[4 * 3 * 3 * 16];    // 2.3 KB  [ic][dh][dw][oc*4+dt]
  const int tid = threadIdx.x;
  // weights
  for (int idx = tid; idx < 576; idx += 256) {
    int s  = idx & 15;
    int oc = s >> 2, dt = s & 3;
    int rest = idx >> 4;
    int dw = rest % 3;
    int dh = (rest / 3) % 3;
    int ic = rest / 9;
    float v = 0.f;
    if (dt < 3) v = dww[g * 432 + (oc * 4 + ic) * 27 + dt * 9 + dh * 3 + dw];
    wsm[idx] = v;
  }
  const ushort* qsrc = (const ushort*)qkv;
  const int w  = tid & 15;
  const int h  = (tid >> 4) & 7;
  const int ts = tid >> 7;          // 0/1 : t-half
  float acc[4][8];
#pragma unroll
  for (int a = 0; a < 4; ++a)
#pragma unroll
    for (int b = 0; b < 8; ++b) acc[a][b] = 0.f;

#pragma unroll 1
  for (int icp = 0; icp < 2; ++icp) {
    __syncthreads();   // phase boundary (also orders wsm on first pass)
    // stage 2 channels: e = ((ic2*10 + hh)*18 + tt)*18 + ww
    for (int e = tid; e < 2 * 10 * 18 * 18; e += 256) {
      int ww = e % 18;
      int r  = e / 18;
      int tt = r % 18;
      int r2 = r / 18;
      int hh = r2 % 10;
      int ic2 = r2 / 10;
      int gt = tt - 1, gh = h0 - 1 + hh, gw = w0 - 1 + ww;
      ushort v = 0;
      if ((unsigned)gt < 16u && (unsigned)gh < 64u && (unsigned)gw < 64u)
        v = qsrc[(g * 4 + icp * 2 + ic2) * NTOT + gt * 4096 + gh * 64 + gw];
      xs[((ic2 * 10 + hh) * 18 + ww) * 20 + tt] = v;
    }
    __syncthreads();
#pragma unroll 1
    for (int ic2 = 0; ic2 < 2; ++ic2) {
      const ushort* xsl = xs + ic2 * 3600 + ts * 8;
      const float*  wsl = wsm + (icp * 2 + ic2) * 144;
#pragma unroll
      for (int dh = 0; dh < 3; ++dh) {
#pragma unroll
        for (int dw = 0; dw < 3; ++dw) {
          const ushort* col = xsl + ((h + dh) * 18 + (w + dw)) * 20;
          uint2 p0 = *(const uint2*)(col);       // t0..3
          uint2 p1 = *(const uint2*)(col + 4);   // t4..7
          uint  p2 = *(const uint*)(col + 8);    // t8..9
          float xc[10];
          xc[0] = lo2f(p0.x); xc[1] = hi2f(p0.x);
          xc[2] = lo2f(p0.y); xc[3] = hi2f(p0.y);
          xc[4] = lo2f(p1.x); xc[5] = hi2f(p1.x);
          xc[6] = lo2f(p1.y); xc[7] = hi2f(p1.y);
          xc[8] = lo2f(p2);   xc[9] = hi2f(p2);
          const float4* wp = (const float4*)(wsl + (dh * 3 + dw) * 16);
          float4 wv[4] = {wp[0], wp[1], wp[2], wp[3]};   // wv[oc] = {dt0,dt1,dt2,pad}
#pragma unroll
          for (int oc = 0; oc < 4; ++oc) {
            float w0v = wv[oc].x, w1v = wv[oc].y, w2v = wv[oc].z;
#pragma unroll
            for (int it = 0; it < 8; ++it)
              acc[oc][it] = fmaf(w0v, xc[it],
                            fmaf(w1v, xc[it + 1],
                            fmaf(w2v, xc[it + 2], acc[oc][it])));
          }
        }
      }
    }
  }
#pragma unroll
  for (int oc = 0; oc < 4; ++oc)
#pragma unroll
    for (int it = 0; it < 8; ++it)
      out[(g * 4 + oc) * NTOT + (ts * 8 + it) * 4096 + (h0 + h) * 64 + (w0 + w)] =
          __float2bfloat16(acc[oc][it]);
}

// ---------------- K3: partial gram S[c][d] = sum_n q[c][n]k[d][n], plus sum q^2, k^2
__global__ __launch_bounds__(256) void k_attn_part(const bf16* __restrict__ dwout,
                                                   float* __restrict__ pS,
                                                   float* __restrict__ pQ,
                                                   float* __restrict__ pK) {
  const int head = blockIdx.y;
  const int chunk = blockIdx.x;   // 0..127, each 512 n
  const int tid = threadIdx.x;
  const ushort* qb = (const ushort*)dwout + (head * 64) * (size_t)NTOT;
  const ushort* kb = (const ushort*)dwout + (256 + head * 64) * (size_t)NTOT;
  __shared__ float lq[64][68];   // 17.4 KB
  __shared__ float lk[64][68];
  const int ci = tid & 15, di = tid >> 4;
  float acc[4][4] = {};
  float qq = 0.f, kk = 0.f;
  for (int s = 0; s < 8; ++s) {
    const int nb = chunk * 512 + s * 64;
    __syncthreads();
#pragma unroll
    for (int i = 0; i < 2; ++i) {
      int f = tid + i * 256;      // 0..511
      int c = f >> 3, n8 = f & 7;
      uint4 qv = *(const uint4*)(qb + c * NTOT + nb + n8 * 8);
      uint4 kv = *(const uint4*)(kb + c * NTOT + nb + n8 * 8);
      int r = n8 * 8;
      lq[r + 0][c] = lo2f(qv.x); lq[r + 1][c] = hi2f(qv.x);
      lq[r + 2][c] = lo2f(qv.y); lq[r + 3][c] = hi2f(qv.y);
      lq[r + 4][c] = lo2f(qv.z); lq[r + 5][c] = hi2f(qv.z);
      lq[r + 6][c] = lo2f(qv.w); lq[r + 7][c] = hi2f(qv.w);
      lk[r + 0][c] = lo2f(kv.x); lk[r + 1][c] = hi2f(kv.x);
      lk[r + 2][c] = lo2f(kv.y); lk[r + 3][c] = hi2f(kv.y);
      lk[r + 4][c] = lo2f(kv.z); lk[r + 5][c] = hi2f(kv.z);
      lk[r + 6][c] = lo2f(kv.w); lk[r + 7][c] = hi2f(kv.w);
    }
    __syncthreads();
#pragma unroll 4
    for (int j = 0; j < 64; ++j) {
      float4 q4 = *(const float4*)&lq[j][ci * 4];
      float4 k4 = *(const float4*)&lk[j][di * 4];
      float qa[4] = {q4.x, q4.y, q4.z, q4.w};
      float ka[4] = {k4.x, k4.y, k4.z, k4.w};
#pragma unroll
      for (int a = 0; a < 4; ++a)
#pragma unroll
        for (int b = 0; b < 4; ++b) acc[a][b] = fmaf(qa[a], ka[b], acc[a][b]);
    }
    if (tid < 64) {
#pragma unroll 4
      for (int j = 0; j < 64; ++j) { float v = lq[j][tid]; qq = fmaf(v, v, qq); }
    } else if (tid < 128) {
#pragma unroll 4
      for (int j = 0; j < 64; ++j) { float v = lk[j][tid - 64]; kk = fmaf(v, v, kk); }
    }
  }
  float* ps = pS + (head * 128 + chunk) * 4096;
#pragma unroll
  for (int a = 0; a < 4; ++a) {
    float4 v4 = make_float4(acc[a][0], acc[a][1], acc[a][2], acc[a][3]);
    *(float4*)(ps + (ci * 4 + a) * 64 + di * 4) = v4;
  }
  if (tid < 64) pQ[(head * 128 + chunk) * 64 + tid] = qq;
  else if (tid < 128) pK[(head * 128 + chunk) * 64 + (tid - 64)] = kk;
}

// ---------------- K4a: reduce partials, normalize, temperature, softmax -> A[h][c][d]
__global__ __launch_bounds__(256) void k_softmax(const float* __restrict__ pS,
                                                 const float* __restrict__ pQ,
                                                 const float* __restrict__ pK,
                                                 const float* __restrict__ temp,
                                                 float* __restrict__ A) {
  const int head = blockIdx.x;
  const int tid = threadIdx.x;
  __shared__ float rq[64], rk[64];
  if (tid < 64) {
    float s = 0.f;
    for (int ch = 0; ch < 128; ++ch) s += pQ[(head * 128 + ch) * 64 + tid];
    rq[tid] = 1.f / fmaxf(sqrtf(s), 1e-12f);
  } else if (tid < 128) {
    float s = 0.f;
    for (int ch = 0; ch < 128; ++ch) s += pK[(head * 128 + ch) * 64 + (tid - 64)];
    rk[tid - 64] = 1.f / fmaxf(sqrtf(s), 1e-12f);
  }
  __syncthreads();
  const int c = tid >> 2, r = tid & 3;
  float4 a0 = {0,0,0,0}, a1 = {0,0,0,0}, a2 = {0,0,0,0}, a3 = {0,0,0,0};
  const float* base = pS + head * 128 * 4096 + c * 64 + r * 16;
  for (int ch = 0; ch < 128; ++ch) {
    const float* p = base + ch * 4096;
    float4 b0 = *(const float4*)(p + 0);
    float4 b1 = *(const float4*)(p + 4);
    float4 b2 = *(const float4*)(p + 8);
    float4 b3 = *(const float4*)(p + 12);
    a0.x += b0.x; a0.y += b0.y; a0.z += b0.z; a0.w += b0.w;
    a1.x += b1.x; a1.y += b1.y; a1.z += b1.z; a1.w += b1.w;
    a2.x += b2.x; a2.y += b2.y; a2.z += b2.z; a2.w += b2.w;
    a3.x += b3.x; a3.y += b3.y; a3.z += b3.z; a3.w += b3.w;
  }
  float v[16] = {a0.x, a0.y, a0.z, a0.w, a1.x, a1.y, a1.z, a1.w,
                 a2.x, a2.y, a2.z, a2.w, a3.x, a3.y, a3.z, a3.w};
  const float tmp = temp[head];
  const float rqc = rq[c];
#pragma unroll
  for (int dd = 0; dd < 16; ++dd) v[dd] = v[dd] * rqc * rk[r * 16 + dd] * tmp;
  float m = v[0];
#pragma unroll
  for (int dd = 1; dd < 16; ++dd) m = fmaxf(m, v[dd]);
  m = fmaxf(m, __shfl_xor(m, 1));
  m = fmaxf(m, __shfl_xor(m, 2));
  float s = 0.f;
#pragma unroll
  for (int dd = 0; dd < 16; ++dd) { v[dd] = expf(v[dd] - m); s += v[dd]; }
  s += __shfl_xor(s, 1);
  s += __shfl_xor(s, 2);
  const float inv = 1.f / s;
  float* ao = A + head * 4096 + c * 64 + r * 16;
#pragma unroll
  for (int q4 = 0; q4 < 4; ++q4) {
    float4 o = make_float4(v[q4*4+0]*inv, v[q4*4+1]*inv, v[q4*4+2]*inv, v[q4*4+3]*inv);
    *(float4*)(ao + q4 * 4) = o;
  }
}

// ---------------- K4b: fold proj into attn:  Mt[h*64+d][oc] = sum_c pw[oc][h*64+c]*A[h][c][d]
__global__ __launch_bounds__(64) void k_mt(const float* __restrict__ pw,
                                           const float* __restrict__ A,
                                           float* __restrict__ Mt) {
  const int hd = blockIdx.x;   // 0..255
  const int h = hd >> 6, d = hd & 63;
  const int oc = threadIdx.x;  // 0..63
  float s = 0.f;
  for (int c = 0; c < 64; ++c)
    s = fmaf(pw[oc * 256 + h * 64 + c], A[(h * 64 + c) * 64 + d], s);
  Mt[hd * 64 + oc] = s;
}

// ---------------- K5: y[oc][n] = sum_hd Mt[hd][oc] * v[hd][n]  (PV + proj fused)
__global__ __launch_bounds__(256) void k_pv(const bf16* __restrict__ dwout,
                                            const float* __restrict__ Mt,
                                            float* __restrict__ y) {
  const int n0 = blockIdx.x * 64;
  const ushort* vb = (const ushort*)dwout + 512 * (size_t)NTOT;
  __shared__ float lv[256][64];   // 64 KB
  const int tid = threadIdx.x;
#pragma unroll
  for (int i = 0; i < 8; ++i) {
    int f = tid + i * 256;        // 0..2047
    int hd = f >> 3, n8 = f & 7;
    uint4 v = *(const uint4*)(vb + hd * NTOT + n0 + n8 * 8);
    float4 a = make_float4(lo2f(v.x), hi2f(v.x), lo2f(v.y), hi2f(v.y));
    float4 b = make_float4(lo2f(v.z), hi2f(v.z), lo2f(v.w), hi2f(v.w));
    *(float4*)&lv[hd][n8 * 8]     = a;
    *(float4*)&lv[hd][n8 * 8 + 4] = b;
  }
  __syncthreads();
  const int oci = tid >> 4, ni = tid & 15;
  float acc[4][4] = {};
#pragma unroll 4
  for (int k = 0; k < 256; ++k) {
    float4 mv = *(const float4*)(Mt + k * 64 + oci * 4);
    float4 vv = *(const float4*)&lv[k][ni * 4];
    float ma[4] = {mv.x, mv.y, mv.z, mv.w};
    float va[4] = {vv.x, vv.y, vv.z, vv.w};
#pragma unroll
    for (int a = 0; a < 4; ++a)
#pragma unroll
      for (int b = 0; b < 4; ++b) acc[a][b] = fmaf(ma[a], va[b], acc[a][b]);
  }
#pragma unroll
  for (int a = 0; a < 4; ++a) {
    float4 o = make_float4(acc[a][0], acc[a][1], acc[a][2], acc[a][3]);
    *(float4*)(y + (oci * 4 + a) * NTOT + n0 + ni * 4) = o;
  }
}

extern "C" void kernel_launch(void* const* d_in, const int* in_sizes, int n_in,
                              void* d_out, int out_size, void* d_ws, size_t ws_size,
                              hipStream_t stream) {
  const float* x      = (const float*)d_in[0];
  const float* qkv_w  = (const float*)d_in[1];
  const float* dw_w   = (const float*)d_in[2];
  const float* proj_w = (const float*)d_in[3];
  const float* temp   = (const float*)d_in[4];
  float* out = (float*)d_out;

  char* w8 = (char*)d_ws;
  bf16*  qkv   = (bf16*)(w8);                          // 768*65536 bf16 = 100,663,296 B
  bf16*  dwout = (bf16*)(w8 + 100663296ull);           // 768*65536 bf16 = 100,663,296 B
  float* pS    = (float*)(w8 + 201326592ull);          // 4*128*4096 f32 = 8,388,608 B
  float* pQ    = (float*)(w8 + 209715200ull);          // 32768 f32
  float* pK    = (float*)(w8 + 209846272ull);          // 32768 f32
  float* A     = (float*)(w8 + 209977344ull);          // 16384 f32
  float* Mt    = (float*)(w8 + 210042880ull);          // 16384 f32
  // total 210,108,416 B

  k_qkv<<<dim3(1024, 12), 256, 0, stream>>>(x, qkv_w, qkv);
  k_dwconv<<<dim3(32, 192), 256, 0, stream>>>(qkv, dw_w, dwout);
  k_attn_part<<<dim3(128, 4), 256, 0, stream>>>(dwout, pS, pQ, pK);
  k_softmax<<<4, 256, 0, stream>>>(pS, pQ, pK, temp, A);
  k_mt<<<256, 64, 0, stream>>>(proj_w, A, Mt);
  k_pv<<<1024, 256, 0, stream>>>(dwout, Mt, out);
}

// Round 9
// 414.947 us; speedup vs baseline: 1.8701x; 1.0781x over previous
//
#include <hip/hip_runtime.h>
#include <hip/hip_bf16.h>
#include <hip/hip_fp16.h>

#define NTOT 65536   // T*H*W

typedef __hip_bfloat16 bf16;
typedef _Float16 h2f16 __attribute__((ext_vector_type(2)));

__device__ __forceinline__ float lo2f(unsigned u) { return __uint_as_float(u << 16); }
__device__ __forceinline__ float hi2f(unsigned u) { return __uint_as_float(u & 0xffff0000u); }
__device__ __forceinline__ ushort f2bs(float f) {
  bf16 b = __float2bfloat16(f);
  union { bf16 b; ushort u; } cv;
  cv.b = b;
  return cv.u;
}
__device__ __forceinline__ ushort f2hs(float f) {
  __half h = __float2half(f);
  return __half_as_ushort(h);
}
__device__ __forceinline__ float fdot2(unsigned a, unsigned b, float c) {
#if defined(__has_builtin) && __has_builtin(__builtin_amdgcn_fdot2)
  return __builtin_amdgcn_fdot2(__builtin_bit_cast(h2f16, a),
                                __builtin_bit_cast(h2f16, b), c, false);
#else
  __half_raw r0, r1, r2, r3;
  r0.x = (ushort)(a & 0xffff); r1.x = (ushort)(a >> 16);
  r2.x = (ushort)(b & 0xffff); r3.x = (ushort)(b >> 16);
  return fmaf(__half2float(__half(r0)), __half2float(__half(r2)),
         fmaf(__half2float(__half(r1)), __half2float(__half(r3)), c));
#endif
}

// ---------------- K1: 1x1x1 conv as tiled GEMM (f16 out):  qkv[oc][n] = sum_k w[oc][k]*x[k][n]
__global__ __launch_bounds__(256) void k_qkv(const float* __restrict__ x,
                                             const float* __restrict__ w,
                                             ushort* __restrict__ qkv) {
  const int n0  = blockIdx.x * 64;
  const int oct = blockIdx.y;           // 0..11
  __shared__ float Wt[64][68];          // [k][oc]
  __shared__ float Xs[64][68];          // [k][n]
  const int tid = threadIdx.x;
  const float4* w4 = (const float4*)w;
#pragma unroll
  for (int i = 0; i < 4; ++i) {
    int idx = tid + i * 256;            // 0..1023
    int oc = idx >> 4, kq = idx & 15;
    float4 wv = w4[(oct * 64 + oc) * 16 + kq];
    Wt[kq * 4 + 0][oc] = wv.x;
    Wt[kq * 4 + 1][oc] = wv.y;
    Wt[kq * 4 + 2][oc] = wv.z;
    Wt[kq * 4 + 3][oc] = wv.w;
    int k = idx >> 4, c4 = idx & 15;
    *(float4*)&Xs[k][c4 * 4] = *(const float4*)(x + k * NTOT + n0 + c4 * 4);
  }
  __syncthreads();
  const int oci = tid >> 4, ni = tid & 15;
  float acc[4][4] = {};
#pragma unroll 8
  for (int k = 0; k < 64; ++k) {
    float4 wf = *(const float4*)&Wt[k][oci * 4];
    float4 xf = *(const float4*)&Xs[k][ni * 4];
    float wa[4] = {wf.x, wf.y, wf.z, wf.w};
    float xa[4] = {xf.x, xf.y, xf.z, xf.w};
#pragma unroll
    for (int a = 0; a < 4; ++a)
#pragma unroll
      for (int b = 0; b < 4; ++b) acc[a][b] = fmaf(wa[a], xa[b], acc[a][b]);
  }
#pragma unroll
  for (int a = 0; a < 4; ++a) {
    const int oc = oct * 64 + oci * 4 + a;
    ushort4 o;
    o.x = f2hs(acc[a][0]);
    o.y = f2hs(acc[a][1]);
    o.z = f2hs(acc[a][2]);
    o.w = f2hs(acc[a][3]);
    *(ushort4*)(qkv + (size_t)oc * NTOT + n0 + ni * 4) = o;
  }
}

// ---------------- K2: grouped 3x3x3 conv via f16 dot2, ic phased 2-at-a-time
__global__ __launch_bounds__(256) void k_dwconv(const ushort* __restrict__ qkv,
                                                const float* __restrict__ dww,
                                                bf16* __restrict__ out) {
  const int g  = blockIdx.y;        // 0..191
  const int wt = blockIdx.x & 3;    // 4 w-tiles of 16
  const int ht = blockIdx.x >> 2;   // 8 h-tiles of 8
  const int h0 = ht * 8, w0 = wt * 16;
  __shared__ __align__(16) ushort xs[2 * 10 * 18 * 20];  // 14.4 KB  [ic2][hh][ww][tt20]
  __shared__ __align__(16) unsigned wpk[36 * 8];         // 1.15 KB  [tap][w01 oc0..3, w20 oc0..3]
  const int tid = threadIdx.x;
  // ---- zero the tt=18,19 pad of every column (never touched by staging; read by
  //      the uint2 tail load and multiplied by the 0 weight -> must not be NaN bits)
  for (int r = tid; r < 2 * 10 * 18; r += 256)
    *(unsigned*)(xs + r * 20 + 18) = 0u;
  // ---- pack weights: w01={dt0,dt1} f16-pair, w20={dt2,0}
  for (int idx = tid; idx < 288; idx += 256) {
    int tap = idx >> 3, s = idx & 7;
    int kind = s >> 2, oc = s & 3;
    int ic = tap / 9, r = tap - ic * 9;          // r = dh*3+dw
    const float* wb = dww + g * 432 + (oc * 4 + ic) * 27 + r;
    ushort lo, hi;
    if (kind == 0) { lo = f2hs(wb[0]); hi = f2hs(wb[9]); }
    else           { lo = f2hs(wb[18]); hi = 0; }
    wpk[tap * 8 + kind * 4 + oc] = (unsigned)lo | ((unsigned)hi << 16);
  }
  // ---- thread-fixed staging decomposition ((tt,ww) plane = 18x18 = 324 slots)
  const int ww0 = tid % 18, tt0 = tid / 18;
  const int e1 = tid + 256;
  const int ww1 = e1 % 18, tt1 = e1 / 18;
  const bool s1 = tid < 68;                       // 324-256
  const int gw0 = w0 - 1 + ww0, gt0 = tt0 - 1;
  const int gw1 = w0 - 1 + ww1, gt1 = tt1 - 1;
  const bool v0 = ((unsigned)gt0 < 16u) && ((unsigned)gw0 < 64u);
  const bool v1 = ((unsigned)gt1 < 16u) && ((unsigned)gw1 < 64u);
  const int go0 = v0 ? gt0 * 4096 + gw0 : 0;
  const int go1 = v1 ? gt1 * 4096 + gw1 : 0;
  const int ds0 = ww0 * 20 + tt0;
  const int ds1 = ww1 * 20 + tt1;

  const int w  = tid & 15;
  const int h  = (tid >> 4) & 7;
  const int ts = tid >> 7;          // 0/1 : t-half
  float acc[4][8];
#pragma unroll
  for (int a = 0; a < 4; ++a)
#pragma unroll
    for (int b = 0; b < 8; ++b) acc[a][b] = 0.f;

#pragma unroll 1
  for (int icp = 0; icp < 2; ++icp) {
    __syncthreads();   // phase boundary (orders pad-zeroing + wpk on first pass)
#pragma unroll 1
    for (int ic2 = 0; ic2 < 2; ++ic2) {
      const ushort* cb = qkv + (size_t)(g * 4 + icp * 2 + ic2) * NTOT;
      ushort* xrow = xs + ic2 * 3600;
#pragma unroll 1
      for (int hh = 0; hh < 10; ++hh) {
        const int gh = h0 - 1 + hh;               // wave-uniform
        ushort x0 = 0, x1 = 0;
        if ((unsigned)gh < 64u) {
          const ushort* rb = cb + gh * 64;
          ushort t0 = rb[go0];
          if (v0) x0 = t0;
          if (s1) { ushort t1 = rb[go1]; if (v1) x1 = t1; }
        }
        xrow[hh * 360 + ds0] = x0;
        if (s1) xrow[hh * 360 + ds1] = x1;
      }
    }
    __syncthreads();
    // ---- compute
#pragma unroll
    for (int ic2 = 0; ic2 < 2; ++ic2) {
      const ushort* xsl = xs + ic2 * 3600 + ts * 8;
      const unsigned* wtp = wpk + (icp * 2 + ic2) * 72;   // 9 taps * 8
#pragma unroll
      for (int dh = 0; dh < 3; ++dh) {
#pragma unroll
        for (int dw = 0; dw < 3; ++dw) {
          const ushort* col = xsl + ((h + dh) * 18 + (w + dw)) * 20;
          uint2 a0 = *(const uint2*)(col);        // x0..x3
          uint2 a1 = *(const uint2*)(col + 4);    // x4..x7
          uint2 a2 = *(const uint2*)(col + 8);    // x8..x11 (tail zero-padded)
          unsigned P[10];
          P[0] = a0.x; P[2] = a0.y; P[4] = a1.x; P[6] = a1.y; P[8] = a2.x;
          P[1] = (a0.x >> 16) | (a0.y << 16);
          P[3] = (a0.y >> 16) | (a1.x << 16);
          P[5] = (a1.x >> 16) | (a1.y << 16);
          P[7] = (a1.y >> 16) | (a2.x << 16);
          P[9] = (a2.x >> 16) | (a2.y << 16);
          const uint4 W01 = *(const uint4*)(wtp + (dh * 3 + dw) * 8);
          const uint4 W20 = *(const uint4*)(wtp + (dh * 3 + dw) * 8 + 4);
          const unsigned a01[4] = {W01.x, W01.y, W01.z, W01.w};
          const unsigned a20[4] = {W20.x, W20.y, W20.z, W20.w};
#pragma unroll
          for (int oc = 0; oc < 4; ++oc) {
#pragma unroll
            for (int it = 0; it < 8; ++it)
              acc[oc][it] = fdot2(a01[oc], P[it], fdot2(a20[oc], P[it + 2], acc[oc][it]));
          }
        }
      }
    }
  }
#pragma unroll
  for (int oc = 0; oc < 4; ++oc)
#pragma unroll
    for (int it = 0; it < 8; ++it)
      out[(g * 4 + oc) * NTOT + (ts * 8 + it) * 4096 + (h0 + h) * 64 + (w0 + w)] =
          __float2bfloat16(acc[oc][it]);
}

// ---------------- K3: partial gram S[c][d] = sum_n q[c][n]k[d][n], plus sum q^2, k^2
__global__ __launch_bounds__(256) void k_attn_part(const bf16* __restrict__ dwout,
                                                   float* __restrict__ pS,
                                                   float* __restrict__ pQ,
                                                   float* __restrict__ pK) {
  const int head = blockIdx.y;
  const int chunk = blockIdx.x;   // 0..127, each 512 n
  const int tid = threadIdx.x;
  const ushort* qb = (const ushort*)dwout + (head * 64) * (size_t)NTOT;
  const ushort* kb = (const ushort*)dwout + (256 + head * 64) * (size_t)NTOT;
  __shared__ float lq[64][68];   // 17.4 KB
  __shared__ float lk[64][68];
  const int ci = tid & 15, di = tid >> 4;
  float acc[4][4] = {};
  float qq = 0.f, kk = 0.f;
  for (int s = 0; s < 8; ++s) {
    const int nb = chunk * 512 + s * 64;
    __syncthreads();
#pragma unroll
    for (int i = 0; i < 2; ++i) {
      int f = tid + i * 256;      // 0..511
      int c = f >> 3, n8 = f & 7;
      uint4 qv = *(const uint4*)(qb + c * NTOT + nb + n8 * 8);
      uint4 kv = *(const uint4*)(kb + c * NTOT + nb + n8 * 8);
      int r = n8 * 8;
      lq[r + 0][c] = lo2f(qv.x); lq[r + 1][c] = hi2f(qv.x);
      lq[r + 2][c] = lo2f(qv.y); lq[r + 3][c] = hi2f(qv.y);
      lq[r + 4][c] = lo2f(qv.z); lq[r + 5][c] = hi2f(qv.z);
      lq[r + 6][c] = lo2f(qv.w); lq[r + 7][c] = hi2f(qv.w);
      lk[r + 0][c] = lo2f(kv.x); lk[r + 1][c] = hi2f(kv.x);
      lk[r + 2][c] = lo2f(kv.y); lk[r + 3][c] = hi2f(kv.y);
      lk[r + 4][c] = lo2f(kv.z); lk[r + 5][c] = hi2f(kv.z);
      lk[r + 6][c] = lo2f(kv.w); lk[r + 7][c] = hi2f(kv.w);
    }
    __syncthreads();
#pragma unroll 4
    for (int j = 0; j < 64; ++j) {
      float4 q4 = *(const float4*)&lq[j][ci * 4];
      float4 k4 = *(const float4*)&lk[j][di * 4];
      float qa[4] = {q4.x, q4.y, q4.z, q4.w};
      float ka[4] = {k4.x, k4.y, k4.z, k4.w};
#pragma unroll
      for (int a = 0; a < 4; ++a)
#pragma unroll
        for (int b = 0; b < 4; ++b) acc[a][b] = fmaf(qa[a], ka[b], acc[a][b]);
    }
    if (tid < 64) {
#pragma unroll 4
      for (int j = 0; j < 64; ++j) { float v = lq[j][tid]; qq = fmaf(v, v, qq); }
    } else if (tid < 128) {
#pragma unroll 4
      for (int j = 0; j < 64; ++j) { float v = lk[j][tid - 64]; kk = fmaf(v, v, kk); }
    }
  }
  float* ps = pS + (head * 128 + chunk) * 4096;
#pragma unroll
  for (int a = 0; a < 4; ++a) {
    float4 v4 = make_float4(acc[a][0], acc[a][1], acc[a][2], acc[a][3]);
    *(float4*)(ps + (ci * 4 + a) * 64 + di * 4) = v4;
  }
  if (tid < 64) pQ[(head * 128 + chunk) * 64 + tid] = qq;
  else if (tid < 128) pK[(head * 128 + chunk) * 64 + (tid - 64)] = kk;
}

// ---------------- K4a: reduce partials, normalize, temperature, softmax -> A[h][c][d]
__global__ __launch_bounds__(256) void k_softmax(const float* __restrict__ pS,
                                                 const float* __restrict__ pQ,
                                                 const float* __restrict__ pK,
                                                 const float* __restrict__ temp,
                                                 float* __restrict__ A) {
  const int head = blockIdx.x;
  const int tid = threadIdx.x;
  __shared__ float rq[64], rk[64];
  if (tid < 64) {
    float s = 0.f;
    for (int ch = 0; ch < 128; ++ch) s += pQ[(head * 128 + ch) * 64 + tid];
    rq[tid] = 1.f / fmaxf(sqrtf(s), 1e-12f);
  } else if (tid < 128) {
    float s = 0.f;
    for (int ch = 0; ch < 128; ++ch) s += pK[(head * 128 + ch) * 64 + (tid - 64)];
    rk[tid - 64] = 1.f / fmaxf(sqrtf(s), 1e-12f);
  }
  __syncthreads();
  const int c = tid >> 2, r = tid & 3;
  float4 a0 = {0,0,0,0}, a1 = {0,0,0,0}, a2 = {0,0,0,0}, a3 = {0,0,0,0};
  const float* base = pS + head * 128 * 4096 + c * 64 + r * 16;
  for (int ch = 0; ch < 128; ++ch) {
    const float* p = base + ch * 4096;
    float4 b0 = *(const float4*)(p + 0);
    float4 b1 = *(const float4*)(p + 4);
    float4 b2 = *(const float4*)(p + 8);
    float4 b3 = *(const float4*)(p + 12);
    a0.x += b0.x; a0.y += b0.y; a0.z += b0.z; a0.w += b0.w;
    a1.x += b1.x; a1.y += b1.y; a1.z += b1.z; a1.w += b1.w;
    a2.x += b2.x; a2.y += b2.y; a2.z += b2.z; a2.w += b2.w;
    a3.x += b3.x; a3.y += b3.y; a3.z += b3.z; a3.w += b3.w;
  }
  float v[16] = {a0.x, a0.y, a0.z, a0.w, a1.x, a1.y, a1.z, a1.w,
                 a2.x, a2.y, a2.z, a2.w, a3.x, a3.y, a3.z, a3.w};
  const float tmp = temp[head];
  const float rqc = rq[c];
#pragma unroll
  for (int dd = 0; dd < 16; ++dd) v[dd] = v[dd] * rqc * rk[r * 16 + dd] * tmp;
  float m = v[0];
#pragma unroll
  for (int dd = 1; dd < 16; ++dd) m = fmaxf(m, v[dd]);
  m = fmaxf(m, __shfl_xor(m, 1));
  m = fmaxf(m, __shfl_xor(m, 2));
  float s = 0.f;
#pragma unroll
  for (int dd = 0; dd < 16; ++dd) { v[dd] = expf(v[dd] - m); s += v[dd]; }
  s += __shfl_xor(s, 1);
  s += __shfl_xor(s, 2);
  const float inv = 1.f / s;
  float* ao = A + head * 4096 + c * 64 + r * 16;
#pragma unroll
  for (int q4 = 0; q4 < 4; ++q4) {
    float4 o = make_float4(v[q4*4+0]*inv, v[q4*4+1]*inv, v[q4*4+2]*inv, v[q4*4+3]*inv);
    *(float4*)(ao + q4 * 4) = o;
  }
}

// ---------------- K4b: fold proj into attn:  Mt[h*64+d][oc] = sum_c pw[oc][h*64+c]*A[h][c][d]
__global__ __launch_bounds__(64) void k_mt(const float* __restrict__ pw,
                                           const float* __restrict__ A,
                                           float* __restrict__ Mt) {
  const int hd = blockIdx.x;   // 0..255
  const int h = hd >> 6, d = hd & 63;
  const int oc = threadIdx.x;  // 0..63
  float s = 0.f;
  for (int c = 0; c < 64; ++c)
    s = fmaf(pw[oc * 256 + h * 64 + c], A[(h * 64 + c) * 64 + d], s);
  Mt[hd * 64 + oc] = s;
}

// ---------------- K5: y[oc][n] = sum_hd Mt[hd][oc] * v[hd][n]  (PV + proj fused)
__global__ __launch_bounds__(256) void k_pv(const bf16* __restrict__ dwout,
                                            const float* __restrict__ Mt,
                                            float* __restrict__ y) {
  const int n0 = blockIdx.x * 64;
  const ushort* vb = (const ushort*)dwout + 512 * (size_t)NTOT;
  __shared__ float lv[256][64];   // 64 KB
  const int tid = threadIdx.x;
#pragma unroll
  for (int i = 0; i < 8; ++i) {
    int f = tid + i * 256;        // 0..2047
    int hd = f >> 3, n8 = f & 7;
    uint4 v = *(const uint4*)(vb + hd * NTOT + n0 + n8 * 8);
    float4 a = make_float4(lo2f(v.x), hi2f(v.x), lo2f(v.y), hi2f(v.y));
    float4 b = make_float4(lo2f(v.z), hi2f(v.z), lo2f(v.w), hi2f(v.w));
    *(float4*)&lv[hd][n8 * 8]     = a;
    *(float4*)&lv[hd][n8 * 8 + 4] = b;
  }
  __syncthreads();
  const int oci = tid >> 4, ni = tid & 15;
  float acc[4][4] = {};
#pragma unroll 4
  for (int k = 0; k < 256; ++k) {
    float4 mv = *(const float4*)(Mt + k * 64 + oci * 4);
    float4 vv = *(const float4*)&lv[k][ni * 4];
    float ma[4] = {mv.x, mv.y, mv.z, mv.w};
    float va[4] = {vv.x, vv.y, vv.z, vv.w};
#pragma unroll
    for (int a = 0; a < 4; ++a)
#pragma unroll
      for (int b = 0; b < 4; ++b) acc[a][b] = fmaf(ma[a], va[b], acc[a][b]);
  }
#pragma unroll
  for (int a = 0; a < 4; ++a) {
    float4 o = make_float4(acc[a][0], acc[a][1], acc[a][2], acc[a][3]);
    *(float4*)(y + (oci * 4 + a) * NTOT + n0 + ni * 4) = o;
  }
}

extern "C" void kernel_launch(void* const* d_in, const int* in_sizes, int n_in,
                              void* d_out, int out_size, void* d_ws, size_t ws_size,
                              hipStream_t stream) {
  const float* x      = (const float*)d_in[0];
  const float* qkv_w  = (const float*)d_in[1];
  const float* dw_w   = (const float*)d_in[2];
  const float* proj_w = (const float*)d_in[3];
  const float* temp   = (const float*)d_in[4];
  float* out = (float*)d_out;

  char* w8 = (char*)d_ws;
  ushort* qkv  = (ushort*)(w8);                        // 768*65536 f16  = 100,663,296 B
  bf16*  dwout = (bf16*)(w8 + 100663296ull);           // 768*65536 bf16 = 100,663,296 B
  float* pS    = (float*)(w8 + 201326592ull);          // 4*128*4096 f32 = 8,388,608 B
  float* pQ    = (float*)(w8 + 209715200ull);          // 32768 f32
  float* pK    = (float*)(w8 + 209846272ull);          // 32768 f32
  float* A     = (float*)(w8 + 209977344ull);          // 16384 f32
  float* Mt    = (float*)(w8 + 210042880ull);          // 16384 f32
  // total 210,108,416 B

  k_qkv<<<dim3(1024, 12), 256, 0, stream>>>(x, qkv_w, qkv);
  k_dwconv<<<dim3(32, 192), 256, 0, stream>>>(qkv, dw_w, dwout);
  k_attn_part<<<dim3(128, 4), 256, 0, stream>>>(dwout, pS, pQ, pK);
  k_softmax<<<4, 256, 0, stream>>>(pS, pQ, pK, temp, A);
  k_mt<<<256, 64, 0, stream>>>(proj_w, A, Mt);
  k_pv<<<1024, 256, 0, stream>>>(dwout, Mt, out);
}